// Round 3
// baseline (768.352 us; speedup 1.0000x reference)
//
#include <hip/hip_runtime.h>
#include <hip/hip_bf16.h>
#include <stdint.h>

// GPT self-attention, B=4 S=2048 E=2048 D=2048. FP32 inputs/outputs (per reference
// dtypes); internal compute in bf16 MFMA with fp32 accumulation.
// Round-3 change: rounds 1-2 read the fp32 inputs as bf16 -> ~0.8% of elements hit
// bf16-NaN bit patterns (fp32 mantissa halves with exp bits all-1) -> NaN output.
// Now: convert x,W to bf16 in ws, same GEMM pipeline, fp32 output.
//
// ws (56 MiB): Wqb[8M] Wkb[8M] Wvb[8M] | Sc fp32[16M] (xb bf16 aliases its first
// 8 MiB; proj reads xb before scores overwrites the region) | Kb[8M] Vtb[8M].
// Q_b (bf16) lives in d_out's batch-b fp32 region; pv overwrites it after use.

typedef unsigned short u16;
typedef unsigned int u32;
typedef __bf16 bf16x8 __attribute__((ext_vector_type(8)));
typedef float floatx4 __attribute__((ext_vector_type(4)));

#define DEVI __device__ __forceinline__

constexpr int Bn = 4, Sn = 2048, En = 2048, Dn = 2048;
constexpr int BM = 128, BN = 128, BK = 64;
constexpr int LP = 72;  // LDS pitch (elems): 144 B rows -> conflict-free b128 access

DEVI u16 f2b(float f) {  // round-to-nearest-even f32 -> bf16
  union { float f; u32 u; } v; v.f = f;
  u32 r = v.u + 0x7FFFu + ((v.u >> 16) & 1u);
  return (u16)(r >> 16);
}

// ---- fp32 -> bf16 elementwise, n multiple of 2048; 8 elems/thread.
__global__ __launch_bounds__(256)
void cvt_kernel(const float* __restrict__ src, u16* __restrict__ dst, int n) {
  int i = (blockIdx.x * 256 + threadIdx.x) * 8;
  if (i >= n) return;
  float4 a = *(const float4*)&src[i];
  float4 b = *(const float4*)&src[i + 4];
  *(ushort4*)&dst[i]     = make_ushort4(f2b(a.x), f2b(a.y), f2b(a.z), f2b(a.w));
  *(ushort4*)&dst[i + 4] = make_ushort4(f2b(b.x), f2b(b.y), f2b(b.z), f2b(b.w));
}

// C[m0..+128, n0..+128] += A[*,K] * Bt[*,K]^T (row-major, K contiguous), bf16 in, fp32 acc.
// Fragment maps (verified m89/m91/m92): A-frag A[m=lane&15][k=quad*8+j],
// B-frag Bt[n=lane&15][k=quad*8+j], C/D col=lane&15, row=quad*4+reg.
DEVI void gemm_core(const u16* __restrict__ A, const u16* __restrict__ Bt,
                    int lda, int ldb, int m0, int n0, int kEnd,
                    u16* As, u16* Bs, floatx4 acc[4][4]) {
  const int tid = threadIdx.x;
  const int lane = tid & 63;
  const int wave = tid >> 6;
  const int wm = (wave >> 1) * 64;
  const int wn = (wave & 1) * 64;
  const int quad = lane >> 4;
  const int l16 = lane & 15;

  for (int k0 = 0; k0 < kEnd; k0 += BK) {
    // stage 128x64 A and B tiles: 1024 16B-chunks each, 4 per thread
#pragma unroll
    for (int u = 0; u < 4; ++u) {
      int c = tid + 256 * u;           // chunk id 0..1023
      int row = c >> 3;
      int col = (c & 7) * 8;           // elem col
      *(uint4*)&As[row * LP + col] = *(const uint4*)&A[(size_t)(m0 + row) * lda + k0 + col];
      *(uint4*)&Bs[row * LP + col] = *(const uint4*)&Bt[(size_t)(n0 + row) * ldb + k0 + col];
    }
    __syncthreads();
#pragma unroll
    for (int s = 0; s < 2; ++s) {
      bf16x8 af[4], bfr[4];
#pragma unroll
      for (int i = 0; i < 4; ++i)
        af[i] = *(const bf16x8*)&As[(wm + i * 16 + l16) * LP + s * 32 + quad * 8];
#pragma unroll
      for (int j = 0; j < 4; ++j)
        bfr[j] = *(const bf16x8*)&Bs[(wn + j * 16 + l16) * LP + s * 32 + quad * 8];
#pragma unroll
      for (int i = 0; i < 4; ++i)
#pragma unroll
        for (int j = 0; j < 4; ++j)
          acc[i][j] = __builtin_amdgcn_mfma_f32_16x16x32_bf16(af[i], bfr[j], acc[i][j], 0, 0, 0);
    }
    __syncthreads();
  }
}

// ---- QKV projection for ONE batch: y = x_b @ W^T. z=0->Q_b, z=1->K_b, z=2->Vt_b (transposed).
__global__ __launch_bounds__(256, 2)
void proj_kernel(const u16* __restrict__ x, const u16* __restrict__ Wq,
                 const u16* __restrict__ Wk, const u16* __restrict__ Wv,
                 u16* __restrict__ Q, u16* __restrict__ K, u16* __restrict__ Vt) {
  __shared__ __align__(16) u16 As[BM * LP], Bs[BN * LP];
  const int z = blockIdx.z;
  const u16* W = (z == 0) ? Wq : (z == 1) ? Wk : Wv;
  const int m0 = blockIdx.y * BM, n0 = blockIdx.x * BN;
  floatx4 acc[4][4] = {};
  gemm_core(x, W, En, En, m0, n0, En, As, Bs, acc);

  const int lane = threadIdx.x & 63, wave = threadIdx.x >> 6;
  const int wm = (wave >> 1) * 64, wn = (wave & 1) * 64;
  const int quad = lane >> 4, l16 = lane & 15;

  if (z < 2) {
    u16* dst = (z == 0) ? Q : K;
#pragma unroll
    for (int i = 0; i < 4; ++i) {
      int gm0 = m0 + wm + i * 16 + quad * 4;      // token index
#pragma unroll
      for (int j = 0; j < 4; ++j) {
        int gn = n0 + wn + j * 16 + l16;
#pragma unroll
        for (int r = 0; r < 4; ++r)
          dst[(size_t)(gm0 + r) * Dn + gn] = f2b(acc[i][j][r]);
      }
    }
  } else {
#pragma unroll
    for (int i = 0; i < 4; ++i) {
      int s0 = m0 + wm + i * 16 + quad * 4;       // token index
#pragma unroll
      for (int j = 0; j < 4; ++j) {
        int gn = n0 + wn + j * 16 + l16;          // d index
        *(ushort4*)&Vt[(size_t)gn * Sn + s0] =
            make_ushort4(f2b(acc[i][j][0]), f2b(acc[i][j][1]),
                         f2b(acc[i][j][2]), f2b(acc[i][j][3]));
      }
    }
  }
}

// ---- scores = Q_b @ K_b^T / sqrt(D), causal mask; fully-masked tiles filled with -1e30.
__global__ __launch_bounds__(256, 2)
void scores_kernel(const u16* __restrict__ Q, const u16* __restrict__ K,
                   float* __restrict__ Sc) {
  const int m0 = blockIdx.y * BM, n0 = blockIdx.x * BN;
  if (n0 > m0 + (BM - 1)) {  // fully above diagonal
    for (int idx = threadIdx.x; idx < BM * BN; idx += 256) {
      int r = idx >> 7, c = idx & (BN - 1);
      Sc[(size_t)(m0 + r) * Sn + n0 + c] = -1e30f;
    }
    return;
  }
  __shared__ __align__(16) u16 As[BM * LP], Bs[BN * LP];
  floatx4 acc[4][4] = {};
  gemm_core(Q, K, Dn, Dn, m0, n0, Dn, As, Bs, acc);

  const float inv_scale = 0.022097086912079608f;  // 1/sqrt(2048)
  const int lane = threadIdx.x & 63, wave = threadIdx.x >> 6;
  const int wm = (wave >> 1) * 64, wn = (wave & 1) * 64;
  const int quad = lane >> 4, l16 = lane & 15;
#pragma unroll
  for (int i = 0; i < 4; ++i) {
    int gm0 = m0 + wm + i * 16 + quad * 4;
#pragma unroll
    for (int j = 0; j < 4; ++j) {
      int gn = n0 + wn + j * 16 + l16;
#pragma unroll
      for (int r = 0; r < 4; ++r) {
        float v = acc[i][j][r] * inv_scale;
        if (gn > gm0 + r) v = -1e30f;
        Sc[(size_t)(gm0 + r) * Sn + gn] = v;
      }
    }
  }
}

// ---- row softmax over 2048 fp32; write attn bf16 in-place (u16 pitch stays 2*Sn).
__global__ __launch_bounds__(256)
void softmax_kernel(float* __restrict__ Sc) {
  float* sr = Sc + (size_t)blockIdx.x * Sn;
  const int t = threadIdx.x;
  float4 v0 = ((const float4*)sr)[t];
  float4 v1 = ((const float4*)sr)[t + 256];
  float m = fmaxf(fmaxf(fmaxf(v0.x, v0.y), fmaxf(v0.z, v0.w)),
                  fmaxf(fmaxf(v1.x, v1.y), fmaxf(v1.z, v1.w)));
#pragma unroll
  for (int off = 32; off; off >>= 1) m = fmaxf(m, __shfl_xor(m, off));
  __shared__ float redm[4], reds[4];
  if ((t & 63) == 0) redm[t >> 6] = m;
  __syncthreads();
  m = fmaxf(fmaxf(redm[0], redm[1]), fmaxf(redm[2], redm[3]));

  float e[8];
  e[0] = __expf(v0.x - m); e[1] = __expf(v0.y - m);
  e[2] = __expf(v0.z - m); e[3] = __expf(v0.w - m);
  e[4] = __expf(v1.x - m); e[5] = __expf(v1.y - m);
  e[6] = __expf(v1.z - m); e[7] = __expf(v1.w - m);
  float s = ((e[0] + e[1]) + (e[2] + e[3])) + ((e[4] + e[5]) + (e[6] + e[7]));
#pragma unroll
  for (int off = 32; off; off >>= 1) s += __shfl_xor(s, off);
  if ((t & 63) == 0) reds[t >> 6] = s;
  __syncthreads();
  s = (reds[0] + reds[1]) + (reds[2] + reds[3]);
  float inv = 1.0f / s;

  u16* ar = (u16*)sr;  // all global reads happened before the barriers above
  *(ushort4*)&ar[t * 4] =
      make_ushort4(f2b(e[0] * inv), f2b(e[1] * inv), f2b(e[2] * inv), f2b(e[3] * inv));
  *(ushort4*)&ar[(t + 256) * 4] =
      make_ushort4(f2b(e[4] * inv), f2b(e[5] * inv), f2b(e[6] * inv), f2b(e[7] * inv));
}

// ---- out_b = attn @ V via Vt; K-loop truncated at the diagonal tile. FP32 output.
__global__ __launch_bounds__(256, 2)
void pv_kernel(const float* __restrict__ Sc, const u16* __restrict__ Vt,
               float* __restrict__ out) {
  const int m0 = blockIdx.y * BM, n0 = blockIdx.x * BN;
  __shared__ __align__(16) u16 As[BM * LP], Bs[BN * LP];
  floatx4 acc[4][4] = {};
  const u16* P = (const u16*)Sc;  // bf16 attn, u16 pitch 2*Sn
  gemm_core(P, Vt, 2 * Sn, Sn, m0, n0, m0 + BM, As, Bs, acc);

  const int lane = threadIdx.x & 63, wave = threadIdx.x >> 6;
  const int wm = (wave >> 1) * 64, wn = (wave & 1) * 64;
  const int quad = lane >> 4, l16 = lane & 15;
#pragma unroll
  for (int i = 0; i < 4; ++i) {
    int gm0 = m0 + wm + i * 16 + quad * 4;
#pragma unroll
    for (int j = 0; j < 4; ++j) {
      int gn = n0 + wn + j * 16 + l16;
#pragma unroll
      for (int r = 0; r < 4; ++r)
        out[(size_t)(gm0 + r) * Dn + gn] = acc[i][j][r];
    }
  }
}

extern "C" void kernel_launch(void* const* d_in, const int* in_sizes, int n_in,
                              void* d_out, int out_size, void* d_ws, size_t ws_size,
                              hipStream_t stream) {
  const float* x  = (const float*)d_in[0];   // setup_inputs order: x, Wk, Wq, Wv (fp32)
  const float* Wk = (const float*)d_in[1];
  const float* Wq = (const float*)d_in[2];
  const float* Wv = (const float*)d_in[3];
  float* out = (float*)d_out;

  // ws: Wqb|Wkb|Wvb bf16 [3 * Dn*En] | Sc fp32 [Sn*Sn] (xb bf16 aliased at its base)
  //     | Kb bf16 [Sn*Dn] | Vtb bf16 [Dn*Sn]   == 56 MiB
  u16* Wqb = (u16*)d_ws;
  u16* Wkb = Wqb + (size_t)Dn * En;
  u16* Wvb = Wkb + (size_t)Dn * En;
  float* Sc = (float*)(Wvb + (size_t)Dn * En);
  u16* xb  = (u16*)Sc;                       // alias: dead once scores_kernel runs
  u16* Kb  = (u16*)(Sc + (size_t)Sn * Sn);
  u16* Vtb = Kb + (size_t)Sn * Dn;

  dim3 blk(256);
  const int nW = Dn * En;                    // 4M elems
  cvt_kernel<<<nW / 2048, blk, 0, stream>>>(Wq, Wqb, nW);
  cvt_kernel<<<nW / 2048, blk, 0, stream>>>(Wk, Wkb, nW);
  cvt_kernel<<<nW / 2048, blk, 0, stream>>>(Wv, Wvb, nW);

  for (int b = 0; b < Bn; ++b) {
    const float* xf = x + (size_t)b * Sn * En;
    float* outb = out + (size_t)b * Sn * Dn;
    u16* Qb = (u16*)outb;                    // bf16 Q in out_b's fp32 region; pv overwrites
    cvt_kernel<<<(Sn * En) / 2048, blk, 0, stream>>>(xf, xb, Sn * En);
    proj_kernel<<<dim3(Dn / BN, Sn / BM, 3), blk, 0, stream>>>(xb, Wqb, Wkb, Wvb, Qb, Kb, Vtb);
    scores_kernel<<<dim3(Sn / BN, Sn / BM, 1), blk, 0, stream>>>(Qb, Kb, Sc);
    softmax_kernel<<<dim3(Sn), blk, 0, stream>>>(Sc);
    pv_kernel<<<dim3(Dn / BN, Sn / BM, 1), blk, 0, stream>>>(Sc, Vtb, outb);
  }
}

// Round 4
// 471.446 us; speedup vs baseline: 1.6298x; 1.6298x over previous
//
#include <hip/hip_runtime.h>
#include <hip/hip_bf16.h>
#include <stdint.h>

// GPT self-attention, B=4 S=2048 E=2048 D=2048. FP32 in/out, bf16 MFMA internally.
// Round-4: (1) gemm_core staged via __builtin_amdgcn_global_load_lds width=16
// (m93->m97 ladder step) with XOR source-swizzle (group g of row r stored at
// g^(r&7), unpadded LP=64) -> conflict-free b128 fragment reads under the DMA's
// wave-uniform-base+lane*16 constraint. (2) batch-fused dispatches (8 launches)
// when ws_size >= 184 MiB; proven 56 MiB sequential fallback otherwise.

typedef unsigned short u16;
typedef unsigned int u32;
typedef __bf16 bf16x8 __attribute__((ext_vector_type(8)));
typedef float floatx4 __attribute__((ext_vector_type(4)));

#define DEVI __device__ __forceinline__

constexpr int Bn = 4, Sn = 2048, En = 2048, Dn = 2048;
constexpr int BM = 128, BN = 128, BK = 64;

DEVI u16 f2b(float f) {  // round-to-nearest-even f32 -> bf16
  union { float f; u32 u; } v; v.f = f;
  u32 r = v.u + 0x7FFFu + ((v.u >> 16) & 1u);
  return (u16)(r >> 16);
}

DEVI void cp16(const u16* g, u16* l) {  // async global->LDS, 16 B per lane
  __builtin_amdgcn_global_load_lds(
      (const __attribute__((address_space(1))) void*)g,
      (__attribute__((address_space(3))) void*)l, 16, 0, 0);
}

// ---- fp32 -> bf16 elementwise, n multiple of 2048; 8 elems/thread.
__global__ __launch_bounds__(256)
void cvt_kernel(const float* __restrict__ src, u16* __restrict__ dst, int n) {
  int i = (blockIdx.x * 256 + threadIdx.x) * 8;
  if (i >= n) return;
  float4 a = *(const float4*)&src[i];
  float4 b = *(const float4*)&src[i + 4];
  *(ushort4*)&dst[i]     = make_ushort4(f2b(a.x), f2b(a.y), f2b(a.z), f2b(a.w));
  *(ushort4*)&dst[i + 4] = make_ushort4(f2b(b.x), f2b(b.y), f2b(b.z), f2b(b.w));
}

// C[m0..+128, n0..+128] += A[*,K] * Bt[*,K]^T (row-major, K contiguous), bf16, fp32 acc.
// LDS tiles 128x64 unpadded (LP=64), 8-elem group g of row r stored at g^(r&7).
// Fragment maps (m89/m91/m92): A[m=lane&15][k=quad*8+j], Bt[n=lane&15][k=quad*8+j],
// C/D col=lane&15, row=quad*4+reg.
DEVI void gemm_core(const u16* __restrict__ A, const u16* __restrict__ Bt,
                    int lda, int ldb, int m0, int n0, int kEnd,
                    u16* As, u16* Bs, floatx4 acc[4][4]) {
  const int tid = threadIdx.x;
  const int lane = tid & 63;
  const int wave = tid >> 6;
  const int wm = (wave >> 1) * 64;
  const int wn = (wave & 1) * 64;
  const int quad = lane >> 4;
  const int l16 = lane & 15;
  const int sw = l16 & 7;  // r&7 for fragment rows (wm,wn,i*16 are multiples of 8)

  // per-lane staging coords, constant across k-iters
  int srow[4], sgl[4], sdst[4];
#pragma unroll
  for (int u = 0; u < 4; ++u) {
    int c0 = wave * 256 + u * 64;       // wave-uniform chunk base
    int c = c0 + lane;                  // this lane's 16B chunk
    srow[u] = c >> 3;
    sgl[u] = (c & 7) ^ (srow[u] & 7);   // logical column-group under swizzle
    sdst[u] = c0 * 8;                   // LDS elem offset (wave-uniform)
  }

  for (int k0 = 0; k0 < kEnd; k0 += BK) {
#pragma unroll
    for (int u = 0; u < 4; ++u) {
      cp16(&A[(size_t)(m0 + srow[u]) * lda + k0 + sgl[u] * 8], &As[sdst[u]]);
      cp16(&Bt[(size_t)(n0 + srow[u]) * ldb + k0 + sgl[u] * 8], &Bs[sdst[u]]);
    }
    __syncthreads();  // drains vmcnt -> DMA complete
#pragma unroll
    for (int s = 0; s < 2; ++s) {
      const int gcol = ((s * 4 + quad) ^ sw) * 8;  // swizzled group offset (elems)
      bf16x8 af[4], bfr[4];
#pragma unroll
      for (int i = 0; i < 4; ++i)
        af[i] = *(const bf16x8*)&As[(wm + i * 16 + l16) * 64 + gcol];
#pragma unroll
      for (int j = 0; j < 4; ++j)
        bfr[j] = *(const bf16x8*)&Bs[(wn + j * 16 + l16) * 64 + gcol];
#pragma unroll
      for (int i = 0; i < 4; ++i)
#pragma unroll
        for (int j = 0; j < 4; ++j)
          acc[i][j] = __builtin_amdgcn_mfma_f32_16x16x32_bf16(af[i], bfr[j], acc[i][j], 0, 0, 0);
    }
    __syncthreads();  // all reads done before next iter's DMA overwrite
  }
}

// ---- QKV projection: y = x @ W^T over all tokens passed (grid.y*128 of them).
// z=0->Q, z=1->K (both [t][d]), z=2->V transposed per batch (b = t>>11).
__global__ __launch_bounds__(256, 2)
void proj_kernel(const u16* __restrict__ x, const u16* __restrict__ Wq,
                 const u16* __restrict__ Wk, const u16* __restrict__ Wv,
                 u16* __restrict__ Q, u16* __restrict__ K, u16* __restrict__ Vt) {
  __shared__ __align__(16) u16 As[BM * 64], Bs[BN * 64];
  const int z = blockIdx.z;
  const u16* W = (z == 0) ? Wq : (z == 1) ? Wk : Wv;
  const int m0 = blockIdx.y * BM, n0 = blockIdx.x * BN;
  floatx4 acc[4][4] = {};
  gemm_core(x, W, En, En, m0, n0, En, As, Bs, acc);

  const int lane = threadIdx.x & 63, wave = threadIdx.x >> 6;
  const int wm = (wave >> 1) * 64, wn = (wave & 1) * 64;
  const int quad = lane >> 4, l16 = lane & 15;

  if (z < 2) {
    u16* dst = (z == 0) ? Q : K;
#pragma unroll
    for (int i = 0; i < 4; ++i) {
      int t0 = m0 + wm + i * 16 + quad * 4;       // token index
#pragma unroll
      for (int j = 0; j < 4; ++j) {
        int gn = n0 + wn + j * 16 + l16;
#pragma unroll
        for (int r = 0; r < 4; ++r)
          dst[(size_t)(t0 + r) * Dn + gn] = f2b(acc[i][j][r]);
      }
    }
  } else {
#pragma unroll
    for (int i = 0; i < 4; ++i) {
      int t0 = m0 + wm + i * 16 + quad * 4;       // token index
      int b = t0 >> 11, s0 = t0 & (Sn - 1);
#pragma unroll
      for (int j = 0; j < 4; ++j) {
        int gn = n0 + wn + j * 16 + l16;          // d index
        *(ushort4*)&Vt[((size_t)b * Dn + gn) * Sn + s0] =
            make_ushort4(f2b(acc[i][j][0]), f2b(acc[i][j][1]),
                         f2b(acc[i][j][2]), f2b(acc[i][j][3]));
      }
    }
  }
}

// ---- scores = Q_b @ K_b^T / sqrt(D), causal; z = batch. Skipped tiles -> -1e30.
__global__ __launch_bounds__(256, 2)
void scores_kernel(const u16* __restrict__ Q, const u16* __restrict__ K,
                   float* __restrict__ Sc) {
  const int b = blockIdx.z;
  const int m0 = blockIdx.y * BM, n0 = blockIdx.x * BN;
  float* C = Sc + (size_t)b * Sn * Sn;
  if (n0 > m0 + (BM - 1)) {
    for (int idx = threadIdx.x; idx < BM * BN; idx += 256) {
      int r = idx >> 7, c = idx & (BN - 1);
      C[(size_t)(m0 + r) * Sn + n0 + c] = -1e30f;
    }
    return;
  }
  __shared__ __align__(16) u16 As[BM * 64], Bs[BN * 64];
  floatx4 acc[4][4] = {};
  gemm_core(Q + (size_t)b * Sn * Dn, K + (size_t)b * Sn * Dn, Dn, Dn, m0, n0, Dn,
            As, Bs, acc);

  const float inv_scale = 0.022097086912079608f;  // 1/sqrt(2048)
  const int lane = threadIdx.x & 63, wave = threadIdx.x >> 6;
  const int wm = (wave >> 1) * 64, wn = (wave & 1) * 64;
  const int quad = lane >> 4, l16 = lane & 15;
#pragma unroll
  for (int i = 0; i < 4; ++i) {
    int gm0 = m0 + wm + i * 16 + quad * 4;
#pragma unroll
    for (int j = 0; j < 4; ++j) {
      int gn = n0 + wn + j * 16 + l16;
#pragma unroll
      for (int r = 0; r < 4; ++r) {
        float v = acc[i][j][r] * inv_scale;
        if (gn > gm0 + r) v = -1e30f;
        C[(size_t)(gm0 + r) * Sn + gn] = v;
      }
    }
  }
}

// ---- row softmax over 2048 fp32; write attn bf16 in-place (u16 pitch 2*Sn).
__global__ __launch_bounds__(256)
void softmax_kernel(float* __restrict__ Sc) {
  float* sr = Sc + (size_t)blockIdx.x * Sn;
  const int t = threadIdx.x;
  float4 v0 = ((const float4*)sr)[t];
  float4 v1 = ((const float4*)sr)[t + 256];
  float m = fmaxf(fmaxf(fmaxf(v0.x, v0.y), fmaxf(v0.z, v0.w)),
                  fmaxf(fmaxf(v1.x, v1.y), fmaxf(v1.z, v1.w)));
#pragma unroll
  for (int off = 32; off; off >>= 1) m = fmaxf(m, __shfl_xor(m, off));
  __shared__ float redm[4], reds[4];
  if ((t & 63) == 0) redm[t >> 6] = m;
  __syncthreads();
  m = fmaxf(fmaxf(redm[0], redm[1]), fmaxf(redm[2], redm[3]));

  float e[8];
  e[0] = __expf(v0.x - m); e[1] = __expf(v0.y - m);
  e[2] = __expf(v0.z - m); e[3] = __expf(v0.w - m);
  e[4] = __expf(v1.x - m); e[5] = __expf(v1.y - m);
  e[6] = __expf(v1.z - m); e[7] = __expf(v1.w - m);
  float s = ((e[0] + e[1]) + (e[2] + e[3])) + ((e[4] + e[5]) + (e[6] + e[7]));
#pragma unroll
  for (int off = 32; off; off >>= 1) s += __shfl_xor(s, off);
  if ((t & 63) == 0) reds[t >> 6] = s;
  __syncthreads();
  s = (reds[0] + reds[1]) + (reds[2] + reds[3]);
  float inv = 1.0f / s;

  u16* ar = (u16*)sr;  // all global reads above; in-place bf16 write is safe
  *(ushort4*)&ar[t * 4] =
      make_ushort4(f2b(e[0] * inv), f2b(e[1] * inv), f2b(e[2] * inv), f2b(e[3] * inv));
  *(ushort4*)&ar[(t + 256) * 4] =
      make_ushort4(f2b(e[4] * inv), f2b(e[5] * inv), f2b(e[6] * inv), f2b(e[7] * inv));
}

// ---- out_b = attn @ V via Vt; z = batch; K-loop truncated at diagonal. FP32 out.
__global__ __launch_bounds__(256, 2)
void pv_kernel(const float* __restrict__ Sc, const u16* __restrict__ Vt,
               float* __restrict__ out) {
  const int b = blockIdx.z;
  const int m0 = blockIdx.y * BM, n0 = blockIdx.x * BN;
  __shared__ __align__(16) u16 As[BM * 64], Bs[BN * 64];
  floatx4 acc[4][4] = {};
  const u16* P = (const u16*)(Sc + (size_t)b * Sn * Sn);  // bf16 attn, pitch 2*Sn
  gemm_core(P, Vt + (size_t)b * Dn * Sn, 2 * Sn, Sn, m0, n0, m0 + BM, As, Bs, acc);

  const int lane = threadIdx.x & 63, wave = threadIdx.x >> 6;
  const int wm = (wave >> 1) * 64, wn = (wave & 1) * 64;
  const int quad = lane >> 4, l16 = lane & 15;
  float* ob = out + (size_t)b * Sn * Dn;
#pragma unroll
  for (int i = 0; i < 4; ++i) {
    int gm0 = m0 + wm + i * 16 + quad * 4;
#pragma unroll
    for (int j = 0; j < 4; ++j) {
      int gn = n0 + wn + j * 16 + l16;
#pragma unroll
      for (int r = 0; r < 4; ++r)
        ob[(size_t)(gm0 + r) * Dn + gn] = acc[i][j][r];
    }
  }
}

extern "C" void kernel_launch(void* const* d_in, const int* in_sizes, int n_in,
                              void* d_out, int out_size, void* d_ws, size_t ws_size,
                              hipStream_t stream) {
  const float* x  = (const float*)d_in[0];   // setup_inputs order: x, Wk, Wq, Wv (fp32)
  const float* Wk = (const float*)d_in[1];
  const float* Wq = (const float*)d_in[2];
  const float* Wv = (const float*)d_in[3];
  float* out = (float*)d_out;

  dim3 blk(256);
  const int nW = Dn * En;                    // 4M elems per weight
  const size_t MiB = 1ull << 20;

  if (ws_size >= 184 * MiB) {
    // ---- fused path: Wqb|Wkb|Wvb | xb(all) | K(all) | Vt(all) | Sc(all fp32)
    u16* Wqb = (u16*)d_ws;
    u16* Wkb = Wqb + (size_t)nW;
    u16* Wvb = Wkb + (size_t)nW;
    u16* xb  = Wvb + (size_t)nW;             // [8192][2048]
    u16* Kall = xb + (size_t)Bn * Sn * En;   // [8192][2048]
    u16* Vtall = Kall + (size_t)Bn * Sn * Dn;  // [b][d][s]
    float* Sc = (float*)(Vtall + (size_t)Bn * Dn * Sn);  // [b][s][s]
    u16* Qall = (u16*)out;                   // 32 MiB of the 64 MiB out; pv overwrites

    cvt_kernel<<<nW / 2048, blk, 0, stream>>>(Wq, Wqb, nW);
    cvt_kernel<<<nW / 2048, blk, 0, stream>>>(Wk, Wkb, nW);
    cvt_kernel<<<nW / 2048, blk, 0, stream>>>(Wv, Wvb, nW);
    cvt_kernel<<<(Bn * Sn * En) / 2048, blk, 0, stream>>>(x, xb, Bn * Sn * En);
    proj_kernel<<<dim3(Dn / BN, (Bn * Sn) / BM, 3), blk, 0, stream>>>(
        xb, Wqb, Wkb, Wvb, Qall, Kall, Vtall);
    scores_kernel<<<dim3(Sn / BN, Sn / BM, Bn), blk, 0, stream>>>(Qall, Kall, Sc);
    softmax_kernel<<<dim3(Bn * Sn), blk, 0, stream>>>(Sc);
    pv_kernel<<<dim3(Dn / BN, Sn / BM, Bn), blk, 0, stream>>>(Sc, Vtall, out);
  } else {
    // ---- sequential fallback (proven, 56 MiB): Wqb|Wkb|Wvb | Sc (xb aliased) | Kb | Vtb
    u16* Wqb = (u16*)d_ws;
    u16* Wkb = Wqb + (size_t)nW;
    u16* Wvb = Wkb + (size_t)nW;
    float* Sc = (float*)(Wvb + (size_t)nW);
    u16* xb  = (u16*)Sc;                     // dead once scores_kernel runs
    u16* Kb  = (u16*)(Sc + (size_t)Sn * Sn);
    u16* Vtb = Kb + (size_t)Sn * Dn;

    cvt_kernel<<<nW / 2048, blk, 0, stream>>>(Wq, Wqb, nW);
    cvt_kernel<<<nW / 2048, blk, 0, stream>>>(Wk, Wkb, nW);
    cvt_kernel<<<nW / 2048, blk, 0, stream>>>(Wv, Wvb, nW);
    for (int b = 0; b < Bn; ++b) {
      const float* xf = x + (size_t)b * Sn * En;
      float* outb = out + (size_t)b * Sn * Dn;
      u16* Qb = (u16*)outb;                  // bf16 Q in out_b's region; pv overwrites
      cvt_kernel<<<(Sn * En) / 2048, blk, 0, stream>>>(xf, xb, Sn * En);
      proj_kernel<<<dim3(Dn / BN, Sn / BM, 3), blk, 0, stream>>>(xb, Wqb, Wkb, Wvb,
                                                                 Qb, Kb, Vtb);
      scores_kernel<<<dim3(Sn / BN, Sn / BM, 1), blk, 0, stream>>>(Qb, Kb, Sc);
      softmax_kernel<<<dim3(Sn), blk, 0, stream>>>(Sc);
      pv_kernel<<<dim3(Dn / BN, Sn / BM, 1), blk, 0, stream>>>(Sc, Vtb, outb);
    }
  }
}